// Round 10
// baseline (102.844 us; speedup 1.0000x reference)
//
#include <hip/hip_runtime.h>
#include <hip/hip_bf16.h>

// Problem constants
#define B_    16
#define T_    2048
#define H_    512
#define BT_   32768      // B*T tokens
#define DIN   80         // obs 64 + act 16
#define L_    64
#define C_    32
#define O_    64
#define NSLAB 128        // BT/256 token slabs

typedef __attribute__((ext_vector_type(8))) short short8;
typedef __attribute__((ext_vector_type(4))) float f32x4;
typedef __attribute__((ext_vector_type(4))) float float4v;

__device__ __forceinline__ float bf2f(unsigned short u) {
  union { unsigned int i; float f; } x; x.i = ((unsigned int)u) << 16; return x.f;
}
__device__ __forceinline__ unsigned short f2bf(float f) {
  union { float f; unsigned int i; } x; x.f = f;
  unsigned int r = x.i + 0x7fffu + ((x.i >> 16) & 1u);
  return (unsigned short)(r >> 16);
}

#define WB_N  (H_ * H_)
#define WO_N  (O_ * H_)

// ---------------------------------------------------------------------------
// Kernel 1: embed GEMM with inline prep (identical to R9 — proven).
// u = relu(concat(obs,act) @ We^T + b_e); prologue preps WBb/Woutb/aarr/powa.
// ---------------------------------------------------------------------------
__global__ __launch_bounds__(512) void embed_gemm(
    const float* __restrict__ obs, const float* __restrict__ act,
    const float* __restrict__ W_e, const float* __restrict__ b_e,
    const float* __restrict__ a_raw, const float* __restrict__ W_B,
    const float* __restrict__ W_out,
    unsigned short* __restrict__ WBb, unsigned short* __restrict__ Woutb,
    float* __restrict__ aarr, float* __restrict__ powa,
    unsigned short* __restrict__ u)
{
  __shared__ __align__(16) unsigned char lds[131072];

  const int tid  = threadIdx.x;
  const int lane = tid & 63;
  const int wid  = tid >> 6;
  const int wr   = wid >> 2;
  const int wc   = wid & 3;
  const int cl   = lane & 15;
  const int kgrp = lane >> 4;
  const int rg   = kgrp * 4;

  const int X  = (int)blockIdx.x & 7;
  const int j  = (int)blockIdx.x >> 3;
  const int mt = X * 16 + (j >> 1);
  const int nt = j & 1;
  const int row0 = mt * 256, col0 = nt * 256;

  // Prologue: strided prep
  {
    const int g = (int)blockIdx.x * 512 + tid;
    #pragma unroll
    for (int r = 0; r < 2; ++r) {
      const int idx = g * 2 + r;
      WBb[idx] = f2bf(W_B[idx]);
    }
    if (g < WO_N) Woutb[g] = f2bf(W_out[g]);
    if (g < H_) {
      const float a = tanhf(a_raw[g]);
      aarr[g] = a;
      float p = a;
      #pragma unroll
      for (int i = 0; i < 16; ++i) { powa[i * H_ + g] = p; p *= a; }
    }
  }

  // A-tiles: inline f32->bf16, swizzled ds_write
  {
    const int row  = tid >> 1;
    const int half = tid & 1;
    {
      const float4v* src = (const float4v*)(obs + (size_t)(row0 + row) * 64 + half * 32);
      float f[32];
      #pragma unroll
      for (int i = 0; i < 8; ++i) {
        const float4v t4 = src[i];
        f[i*4+0]=t4[0]; f[i*4+1]=t4[1]; f[i*4+2]=t4[2]; f[i*4+3]=t4[3];
      }
      #pragma unroll
      for (int cc = 0; cc < 4; ++cc) {
        short8 o8;
        #pragma unroll
        for (int jj = 0; jj < 8; ++jj) o8[jj] = (short)f2bf(f[cc*8+jj]);
        const int c16 = half * 4 + cc;
        *(short8*)(lds + row * 128 + ((c16 ^ (row & 7)) << 4)) = o8;
      }
    }
    {
      short8 z8;
      #pragma unroll
      for (int jj = 0; jj < 8; ++jj) z8[jj] = 0;
      if (half == 0) {
        const float4v* asrc = (const float4v*)(act + (size_t)(row0 + row) * 16);
        float g2[16];
        #pragma unroll
        for (int i = 0; i < 4; ++i) {
          const float4v t4 = asrc[i];
          g2[i*4+0]=t4[0]; g2[i*4+1]=t4[1]; g2[i*4+2]=t4[2]; g2[i*4+3]=t4[3];
        }
        #pragma unroll
        for (int cc = 0; cc < 2; ++cc) {
          short8 o8;
          #pragma unroll
          for (int jj = 0; jj < 8; ++jj) o8[jj] = (short)f2bf(g2[cc*8+jj]);
          *(short8*)(lds + 65536 + row * 128 + ((cc ^ (row & 7)) << 4)) = o8;
        }
        #pragma unroll
        for (int cc = 2; cc < 4; ++cc)
          *(short8*)(lds + 65536 + row * 128 + ((cc ^ (row & 7)) << 4)) = z8;
      } else {
        #pragma unroll
        for (int cc = 4; cc < 8; ++cc)
          *(short8*)(lds + 65536 + row * 128 + ((cc ^ (row & 7)) << 4)) = z8;
      }
    }
  }
  // B-tiles: W_e inline f32->bf16
  {
    const int colL = tid >> 1;
    const int col  = col0 + colL;
    const int half = tid & 1;
    {
      const float4v* src = (const float4v*)(W_e + (size_t)col * DIN + half * 32);
      float f[32];
      #pragma unroll
      for (int i = 0; i < 8; ++i) {
        const float4v t4 = src[i];
        f[i*4+0]=t4[0]; f[i*4+1]=t4[1]; f[i*4+2]=t4[2]; f[i*4+3]=t4[3];
      }
      #pragma unroll
      for (int cc = 0; cc < 4; ++cc) {
        short8 o8;
        #pragma unroll
        for (int jj = 0; jj < 8; ++jj) o8[jj] = (short)f2bf(f[cc*8+jj]);
        const int c16 = half * 4 + cc;
        *(short8*)(lds + 32768 + colL * 128 + ((c16 ^ (colL & 7)) << 4)) = o8;
      }
    }
    {
      short8 z8;
      #pragma unroll
      for (int jj = 0; jj < 8; ++jj) z8[jj] = 0;
      if (half == 0) {
        const float4v* src = (const float4v*)(W_e + (size_t)col * DIN + 64);
        float g2[16];
        #pragma unroll
        for (int i = 0; i < 4; ++i) {
          const float4v t4 = src[i];
          g2[i*4+0]=t4[0]; g2[i*4+1]=t4[1]; g2[i*4+2]=t4[2]; g2[i*4+3]=t4[3];
        }
        #pragma unroll
        for (int cc = 0; cc < 2; ++cc) {
          short8 o8;
          #pragma unroll
          for (int jj = 0; jj < 8; ++jj) o8[jj] = (short)f2bf(g2[cc*8+jj]);
          *(short8*)(lds + 98304 + colL * 128 + ((cc ^ (colL & 7)) << 4)) = o8;
        }
        #pragma unroll
        for (int cc = 2; cc < 4; ++cc)
          *(short8*)(lds + 98304 + colL * 128 + ((cc ^ (colL & 7)) << 4)) = z8;
      } else {
        #pragma unroll
        for (int cc = 4; cc < 8; ++cc)
          *(short8*)(lds + 98304 + colL * 128 + ((cc ^ (colL & 7)) << 4)) = z8;
      }
    }
  }
  __syncthreads();

  f32x4 acc[8][4];
  #pragma unroll
  for (int m = 0; m < 8; ++m)
    #pragma unroll
    for (int n = 0; n < 4; ++n) acc[m][n] = f32x4{0.f, 0.f, 0.f, 0.f};

  #pragma unroll
  for (int q = 0; q < 2; ++q) {
    const unsigned char* bufp = lds + q * 65536;
    short8 bfr[4][2];
    #pragma unroll
    for (int n = 0; n < 4; ++n) {
      const int col = wc * 64 + n * 16 + cl;
      #pragma unroll
      for (int ks = 0; ks < 2; ++ks)
        bfr[n][ks] = *(const short8*)(bufp + 32768 + col * 128 +
                                      ((((ks << 2) + kgrp) ^ (col & 7)) << 4));
    }
    #pragma unroll
    for (int g = 0; g < 4; ++g) {
      short8 af[2][2];
      #pragma unroll
      for (int mm = 0; mm < 2; ++mm) {
        const int row = wr * 128 + (g * 2 + mm) * 16 + cl;
        #pragma unroll
        for (int ks = 0; ks < 2; ++ks)
          af[mm][ks] = *(const short8*)(bufp + row * 128 +
                                        ((((ks << 2) + kgrp) ^ (row & 7)) << 4));
      }
      #pragma unroll
      for (int ks = 0; ks < 2; ++ks)
        #pragma unroll
        for (int mm = 0; mm < 2; ++mm)
          #pragma unroll
          for (int n = 0; n < 4; ++n)
            acc[g * 2 + mm][n] = __builtin_amdgcn_mfma_f32_16x16x32_bf16(
                af[mm][ks], bfr[n][ks], acc[g * 2 + mm][n], 0, 0, 0);
    }
  }

  #pragma unroll
  for (int m = 0; m < 8; ++m) {
    #pragma unroll
    for (int n = 0; n < 4; ++n) {
      const int gc = col0 + wc * 64 + n * 16 + cl;
      const float be = b_e[gc];
      #pragma unroll
      for (int e2 = 0; e2 < 4; ++e2) {
        const int gr = row0 + wr * 128 + m * 16 + rg + e2;
        u[(size_t)gr * H_ + gc] = f2bf(fmaxf(acc[m][n][e2] + be, 0.f));
      }
    }
  }
}

// ---------------------------------------------------------------------------
// Kernel 2: FUSED B-projection + diagonal scan + out-projection.
// 256 blocks (128 slabs x 2 h-halves) x 512 threads, 1 block/CU.
//  Phase G: v-acc = u-slab @ WB^T (counted-vmcnt pipeline, unchanged).
//  Phase L: in-place local scan of acc over t (t = wr*128+16m+4kgrp+e2):
//           e2-serial Horner; cross-kgrp prefix via shfl_up with decay
//           (P_k = g_k + a^4 P_{k-1}); cross-band serial carry C; E128 = C.
//  Phase C: publish E_slab = a^128*E128[0]+E128[1] (+release flag); spin on
//           <=7 same-batch predecessor flags (same XCD by mapping; producer
//           bids < consumer bids; all blocks co-resident at 1/CU); Horner
//           with a^256 -> slab carry S; correct acc by a^{t+1}*C_half.
//  Phase O: s -> bf16 swizzled LDS (GEMM LDS dead); MFMA y_part = s @ Wout^T
//           over this h-half -> yp[nt].
// flags zeroed per call by hipMemsetAsync; E reads use agent-scope atomic
// loads (L1-bypass).
// ---------------------------------------------------------------------------
__global__ __launch_bounds__(512) void bproj_scan_out(
    const unsigned short* __restrict__ u, const unsigned short* __restrict__ WBb,
    const unsigned short* __restrict__ Woutb, const float* __restrict__ aarr,
    const float* __restrict__ powa, float* __restrict__ Eslab,
    int* __restrict__ flags, float* __restrict__ yp0, float* __restrict__ yp1)
{
  constexpr int NT = 8;
  __shared__ __align__(16) unsigned char lds[131072];

  const int tid  = threadIdx.x;
  const int lane = tid & 63;
  const int wid  = tid >> 6;
  const int wr   = wid >> 2;
  const int wc   = wid & 3;
  const int cl   = lane & 15;
  const int kgrp = lane >> 4;

  const int X  = (int)blockIdx.x & 7;
  const int j  = (int)blockIdx.x >> 3;
  const int mt = X * 16 + (j >> 1);     // slab (batch = 8 slabs, same XCD)
  const int nt = j & 1;
  const int row0 = mt * 256, col0 = nt * 256;

  auto stageA = [&](int q, int buf) {
    const int k0 = q * 64;
    #pragma unroll
    for (int r = 0; r < 4; ++r) {
      const int o   = r * 8192 + tid * 16;
      const int row = o >> 7;
      const int c16 = (o >> 4) & 7;
      const int kk  = (c16 ^ (row & 7)) << 3;
      __builtin_amdgcn_global_load_lds(
          (const __attribute__((address_space(1))) void*)
              (u + (size_t)(row0 + row) * H_ + k0 + kk),
          (__attribute__((address_space(3))) void*)(lds + buf * 65536 + o),
          16, 0, 0);
    }
  };
  auto stageB_round = [&](int q, int buf, int r) {
    const int k0 = q * 64;
    const int o   = r * 8192 + tid * 16;
    const int col = o >> 7;
    const int c16 = (o >> 4) & 7;
    const int kk  = (c16 ^ (col & 7)) << 3;
    __builtin_amdgcn_global_load_lds(
        (const __attribute__((address_space(1))) void*)
            (WBb + (size_t)(col0 + col) * H_ + k0 + kk),
        (__attribute__((address_space(3))) void*)(lds + buf * 65536 + 32768 + o),
        16, 0, 0);
  };

  f32x4 acc[8][4];
  #pragma unroll
  for (int m = 0; m < 8; ++m)
    #pragma unroll
    for (int n = 0; n < 4; ++n) acc[m][n] = f32x4{0.f, 0.f, 0.f, 0.f};

  // ---- Phase G ----
  stageA(0, 0);
  #pragma unroll
  for (int r = 0; r < 4; ++r) stageB_round(0, 0, r);
  #pragma unroll
  for (int r = 0; r < 4; ++r) stageB_round(1, 1, r);
  asm volatile("s_waitcnt vmcnt(4)" ::: "memory");
  __builtin_amdgcn_sched_barrier(0);
  __builtin_amdgcn_s_barrier();

  for (int q = 0; q < NT; ++q) {
    const int cur = q & 1;
    const unsigned char* bufp = lds + cur * 65536;

    if (q + 1 < NT) stageA(q + 1, cur ^ 1);

    short8 bfr[4][2];
    #pragma unroll
    for (int n = 0; n < 4; ++n) {
      const int col = wc * 64 + n * 16 + cl;
      #pragma unroll
      for (int ks = 0; ks < 2; ++ks)
        bfr[n][ks] = *(const short8*)(bufp + 32768 + col * 128 +
                                      ((((ks << 2) + kgrp) ^ (col & 7)) << 4));
    }
    asm volatile("s_waitcnt lgkmcnt(0)" ::: "memory");
    __builtin_amdgcn_sched_barrier(0);
    __builtin_amdgcn_s_barrier();

    __builtin_amdgcn_s_setprio(1);
    #pragma unroll
    for (int g = 0; g < 4; ++g) {
      if (q + 2 < NT) stageB_round(q + 2, cur, g);
      short8 af[2][2];
      #pragma unroll
      for (int mm = 0; mm < 2; ++mm) {
        const int row = wr * 128 + (g * 2 + mm) * 16 + cl;
        #pragma unroll
        for (int ks = 0; ks < 2; ++ks)
          af[mm][ks] = *(const short8*)(bufp + row * 128 +
                                        ((((ks << 2) + kgrp) ^ (row & 7)) << 4));
      }
      #pragma unroll
      for (int ks = 0; ks < 2; ++ks)
        #pragma unroll
        for (int mm = 0; mm < 2; ++mm)
          #pragma unroll
          for (int n = 0; n < 4; ++n)
            acc[g * 2 + mm][n] = __builtin_amdgcn_mfma_f32_16x16x32_bf16(
                af[mm][ks], bfr[n][ks], acc[g * 2 + mm][n], 0, 0, 0);
    }
    __builtin_amdgcn_s_setprio(0);

    if (q + 2 < NT) {
      asm volatile("s_waitcnt vmcnt(4)" ::: "memory");
    } else if (q + 1 < NT) {
      asm volatile("s_waitcnt vmcnt(0)" ::: "memory");
    }
    __builtin_amdgcn_sched_barrier(0);
    __builtin_amdgcn_s_barrier();
  }

  // ---- Phase L: in-place local scan (per 128-token half, zero init) ----
  float Cn[4];                      // E128 for this (wr, h)
  #pragma unroll
  for (int n = 0; n < 4; ++n) {
    const int h = col0 + wc * 64 + n * 16 + cl;
    const float a1  = aarr[h];
    const float pe0 = powa[0 * H_ + h];     // a^1
    const float pe1 = powa[1 * H_ + h];     // a^2
    const float pe2 = powa[2 * H_ + h];     // a^3
    const float pe3 = powa[3 * H_ + h];     // a^4
    const float a8  = powa[7 * H_ + h];
    const float a16 = powa[15 * H_ + h];
    const float aw0 = powa[(4 * kgrp + 0) * H_ + h];   // a^{4kgrp+1}
    const float aw1 = powa[(4 * kgrp + 1) * H_ + h];
    const float aw2 = powa[(4 * kgrp + 2) * H_ + h];
    const float aw3 = powa[(4 * kgrp + 3) * H_ + h];
    float C = 0.f;
    #pragma unroll
    for (int m = 0; m < 8; ++m) {
      // e2-serial in-group scan (4 consecutive t)
      acc[m][n][1] = fmaf(a1, acc[m][n][0], acc[m][n][1]);
      acc[m][n][2] = fmaf(a1, acc[m][n][1], acc[m][n][2]);
      acc[m][n][3] = fmaf(a1, acc[m][n][2], acc[m][n][3]);
      // cross-kgrp inclusive prefix with decay a^4 (Kogge-Stone)
      float P = acc[m][n][3];
      const float t1 = __shfl_up(P, 16, 64);
      if (kgrp >= 1) P = fmaf(pe3, t1, P);
      const float t2 = __shfl_up(P, 32, 64);
      if (kgrp >= 2) P = fmaf(a8, t2, P);
      float Xc = __shfl_up(P, 16, 64);
      if (kgrp == 0) Xc = 0.f;
      const float bt = __shfl(P, (lane & 15) + 48, 64);   // band end (kgrp 3)
      // corrections: band-local Xc (a^{e2+1}) + cross-band C (a^{4kgrp+e2+1})
      acc[m][n][0] = fmaf(pe0, Xc, fmaf(aw0, C, acc[m][n][0]));
      acc[m][n][1] = fmaf(pe1, Xc, fmaf(aw1, C, acc[m][n][1]));
      acc[m][n][2] = fmaf(pe2, Xc, fmaf(aw2, C, acc[m][n][2]));
      acc[m][n][3] = fmaf(pe3, Xc, fmaf(aw3, C, acc[m][n][3]));
      C = fmaf(a16, C, bt);
    }
    Cn[n] = C;
  }

  // ---- Phase C: E128 -> LDS, publish E_slab, look-back, carry-correct ----
  float* E128 = (float*)lds;            // [2][256] floats (GEMM LDS dead)
  if (kgrp == 0) {
    #pragma unroll
    for (int n = 0; n < 4; ++n)
      E128[wr * 256 + wc * 64 + n * 16 + cl] = Cn[n];
  }
  __syncthreads();
  {
    // publish E_slab (wr==0, kgrp==0 lanes cover all 256 h of this half)
    if (wr == 0 && kgrp == 0) {
      #pragma unroll
      for (int n = 0; n < 4; ++n) {
        const int hl = wc * 64 + n * 16 + cl;
        const int h = col0 + hl;
        const float a16 = powa[15 * H_ + h];
        const float a32 = a16 * a16, a64 = a32 * a32, a128 = a64 * a64;
        Eslab[(size_t)mt * H_ + h] = fmaf(a128, E128[hl], E128[256 + hl]);
      }
    }
  }
  __threadfence();
  __syncthreads();
  if (tid == 0)
    __hip_atomic_store(&flags[mt * 2 + nt], 1, __ATOMIC_RELEASE,
                       __HIP_MEMORY_SCOPE_AGENT);
  const int bs = mt & ~7;               // first slab of this batch
  const int npred = mt - bs;            // 0..7
  if (tid < npred) {
    while (__hip_atomic_load(&flags[(bs + tid) * 2 + nt], __ATOMIC_ACQUIRE,
                             __HIP_MEMORY_SCOPE_AGENT) == 0)
      __builtin_amdgcn_s_sleep(2);
  }
  __syncthreads();

  #pragma unroll
  for (int n = 0; n < 4; ++n) {
    const int hl = wc * 64 + n * 16 + cl;
    const int h = col0 + hl;
    const float a16 = powa[15 * H_ + h];
    const float a32 = a16 * a16, a64 = a32 * a32;
    const float a128 = a64 * a64, a256 = a128 * a128;
    float S = 0.f;
    for (int mp = bs; mp < mt; ++mp) {
      const float ev = __hip_atomic_load(&Eslab[(size_t)mp * H_ + h],
                                         __ATOMIC_RELAXED,
                                         __HIP_MEMORY_SCOPE_AGENT);
      S = fmaf(a256, S, ev);
    }
    const float Ch = (wr == 0) ? S : fmaf(a128, S, E128[hl]);
    const float aw0 = powa[(4 * kgrp + 0) * H_ + h];
    const float aw1 = powa[(4 * kgrp + 1) * H_ + h];
    const float aw2 = powa[(4 * kgrp + 2) * H_ + h];
    const float aw3 = powa[(4 * kgrp + 3) * H_ + h];
    float coef = 1.f;
    #pragma unroll
    for (int m = 0; m < 8; ++m) {
      const float cc = coef * Ch;
      acc[m][n][0] = fmaf(aw0, cc, acc[m][n][0]);
      acc[m][n][1] = fmaf(aw1, cc, acc[m][n][1]);
      acc[m][n][2] = fmaf(aw2, cc, acc[m][n][2]);
      acc[m][n][3] = fmaf(aw3, cc, acc[m][n][3]);
      coef *= a16;
    }
  }
  __syncthreads();   // E128 LDS reads complete before s-tile overwrite

  // ---- Phase O: s -> bf16 swizzled LDS; MFMA out-projection ----
  #pragma unroll
  for (int n = 0; n < 4; ++n) {
    const int h2 = (wc * 64 + n * 16 + cl) * 2;
    #pragma unroll
    for (int m = 0; m < 8; ++m) {
      const int tb = wr * 128 + m * 16 + kgrp * 4;
      #pragma unroll
      for (int e2 = 0; e2 < 4; ++e2) {
        const int t = tb + e2;
        *(unsigned short*)(lds + t * 512 + (h2 ^ ((t & 7) << 4))) =
            f2bf(acc[m][n][e2]);
      }
    }
  }
  __syncthreads();

  f32x4 oacc[2][4];
  #pragma unroll
  for (int mo = 0; mo < 2; ++mo)
    #pragma unroll
    for (int n = 0; n < 4; ++n) oacc[mo][n] = f32x4{0.f, 0.f, 0.f, 0.f};

  #pragma unroll
  for (int ks = 0; ks < 8; ++ks) {
    const int k0 = ks * 32 + kgrp * 8;
    short8 af[2];
    #pragma unroll
    for (int mo = 0; mo < 2; ++mo) {
      const int t = wid * 32 + mo * 16 + cl;
      af[mo] = *(const short8*)(lds + t * 512 + ((k0 * 2) ^ ((t & 7) << 4)));
    }
    #pragma unroll
    for (int n = 0; n < 4; ++n) {
      const short8 bf = *(const short8*)(Woutb + (size_t)(n * 16 + cl) * H_ +
                                         col0 + k0);
      #pragma unroll
      for (int mo = 0; mo < 2; ++mo)
        oacc[mo][n] = __builtin_amdgcn_mfma_f32_16x16x32_bf16(
            af[mo], bf, oacc[mo][n], 0, 0, 0);
    }
  }

  float* yp = nt ? yp1 : yp0;
  #pragma unroll
  for (int mo = 0; mo < 2; ++mo) {
    #pragma unroll
    for (int n = 0; n < 4; ++n) {
      #pragma unroll
      for (int e2 = 0; e2 < 4; ++e2) {
        const int gr = row0 + wid * 32 + mo * 16 + kgrp * 4 + e2;
        const int gc = n * 16 + cl;
        yp[(size_t)gr * O_ + gc] = oacc[mo][n][e2];
      }
    }
  }
}

// ---------------------------------------------------------------------------
// Kernel 3: y = yp0 + yp1 + b_out  (fp32, vectorized x4)
// ---------------------------------------------------------------------------
__global__ __launch_bounds__(256) void ysum(
    const float* __restrict__ yp0, const float* __restrict__ yp1,
    const float* __restrict__ b_out, float* __restrict__ y)
{
  const int g = blockIdx.x * 256 + threadIdx.x;    // over BT*O/4
  const int i4 = g * 4;
  const float4v p0 = ((const float4v*)yp0)[g];
  const float4v p1 = ((const float4v*)yp1)[g];
  const float4v bb = *(const float4v*)(b_out + (i4 & 63));
  float4v o;
  o[0] = p0[0] + p1[0] + bb[0];
  o[1] = p0[1] + p1[1] + bb[1];
  o[2] = p0[2] + p1[2] + bb[2];
  o[3] = p0[3] + p1[3] + bb[3];
  ((float4v*)y)[g] = o;
}

// ---------------------------------------------------------------------------
extern "C" void kernel_launch(void* const* d_in, const int* in_sizes, int n_in,
                              void* d_out, int out_size, void* d_ws, size_t ws_size,
                              hipStream_t stream)
{
  const float* obs   = (const float*)d_in[0];
  const float* act   = (const float*)d_in[1];
  const float* W_e   = (const float*)d_in[2];
  const float* b_e   = (const float*)d_in[3];
  const float* a_raw = (const float*)d_in[4];
  const float* W_B   = (const float*)d_in[5];
  const float* W_out = (const float*)d_in[6];
  const float* b_out = (const float*)d_in[7];
  float* y = (float*)d_out;

  char* w = (char*)d_ws;
  auto carve = [&](size_t bytes) {
    char* p = w; w += (bytes + 255) & ~(size_t)255; return p;
  };
  unsigned short* WBb   = (unsigned short*)carve((size_t)H_ * H_ * 2);
  unsigned short* Woutb = (unsigned short*)carve((size_t)O_ * H_ * 2);
  float*          aarr  = (float*)carve((size_t)H_ * 4);
  float*          powa  = (float*)carve((size_t)16 * H_ * 4);
  unsigned short* u     = (unsigned short*)carve((size_t)BT_ * H_ * 2);   // 33.5 MB
  float*          Eslab = (float*)carve((size_t)NSLAB * H_ * 4);          // 256 KB
  int*            flags = (int*)carve((size_t)NSLAB * 2 * 4);             // 1 KB
  float*          yp0   = (float*)carve((size_t)BT_ * O_ * 4);            // 8.4 MB
  float*          yp1   = (float*)carve((size_t)BT_ * O_ * 4);            // 8.4 MB

  // zero look-back flags (ws is NOT re-poisoned between replays)
  hipMemsetAsync(flags, 0, (size_t)NSLAB * 2 * 4, stream);

  // 1) embed (+ inline weight prep) -> u
  embed_gemm<<<256, 512, 0, stream>>>(obs, act, W_e, b_e, a_raw, W_B, W_out,
                                      WBb, Woutb, aarr, powa, u);
  // 2) fused B-projection + scan + out-projection -> yp0/yp1
  bproj_scan_out<<<256, 512, 0, stream>>>(u, WBb, Woutb, aarr, powa,
                                          Eslab, flags, yp0, yp1);
  // 3) y = yp0 + yp1 + b_out
  ysum<<<(BT_ * O_ / 4) / 256, 256, 0, stream>>>(yp0, yp1, b_out, y);
}

// Round 11
// 71.331 us; speedup vs baseline: 1.4418x; 1.4418x over previous
//
#include <hip/hip_runtime.h>
#include <hip/hip_bf16.h>

// Problem constants
#define B_    16
#define T_    2048
#define H_    512
#define BT_   32768      // B*T tokens
#define DIN   80         // obs 64 + act 16
#define L_    64
#define C_    32
#define O_    64
#define NCHUNK (BT_ / L_)  // 512 chunks

typedef __attribute__((ext_vector_type(8))) short short8;
typedef __attribute__((ext_vector_type(4))) float f32x4;
typedef __attribute__((ext_vector_type(4))) float float4v;

__device__ __forceinline__ float bf2f(unsigned short u) {
  union { unsigned int i; float f; } x; x.i = ((unsigned int)u) << 16; return x.f;
}
__device__ __forceinline__ unsigned short f2bf(float f) {
  union { float f; unsigned int i; } x; x.f = f;
  unsigned int r = x.i + 0x7fffu + ((x.i >> 16) & 1u);
  return (unsigned short)(r >> 16);
}

#define WB_N  (H_ * H_)
#define WO_N  (O_ * H_)

// ---------------------------------------------------------------------------
// Kernel 1: embed GEMM with inline prep (R9-proven, unchanged).
// ---------------------------------------------------------------------------
__global__ __launch_bounds__(512) void embed_gemm(
    const float* __restrict__ obs, const float* __restrict__ act,
    const float* __restrict__ W_e, const float* __restrict__ b_e,
    const float* __restrict__ a_raw, const float* __restrict__ W_B,
    const float* __restrict__ W_out,
    unsigned short* __restrict__ WBb, unsigned short* __restrict__ Woutb,
    float* __restrict__ aarr, float* __restrict__ powa,
    unsigned short* __restrict__ u)
{
  __shared__ __align__(16) unsigned char lds[131072];

  const int tid  = threadIdx.x;
  const int lane = tid & 63;
  const int wid  = tid >> 6;
  const int wr   = wid >> 2;
  const int wc   = wid & 3;
  const int cl   = lane & 15;
  const int kgrp = lane >> 4;
  const int rg   = kgrp * 4;

  const int X  = (int)blockIdx.x & 7;
  const int j  = (int)blockIdx.x >> 3;
  const int mt = X * 16 + (j >> 1);
  const int nt = j & 1;
  const int row0 = mt * 256, col0 = nt * 256;

  // Prologue: strided prep
  {
    const int g = (int)blockIdx.x * 512 + tid;
    #pragma unroll
    for (int r = 0; r < 2; ++r) {
      const int idx = g * 2 + r;
      WBb[idx] = f2bf(W_B[idx]);
    }
    if (g < WO_N) Woutb[g] = f2bf(W_out[g]);
    if (g < H_) {
      const float a = tanhf(a_raw[g]);
      aarr[g] = a;
      float p = a;
      #pragma unroll
      for (int i = 0; i < 16; ++i) { powa[i * H_ + g] = p; p *= a; }
    }
  }

  // A-tiles: inline f32->bf16, swizzled ds_write
  {
    const int row  = tid >> 1;
    const int half = tid & 1;
    {
      const float4v* src = (const float4v*)(obs + (size_t)(row0 + row) * 64 + half * 32);
      float f[32];
      #pragma unroll
      for (int i = 0; i < 8; ++i) {
        const float4v t4 = src[i];
        f[i*4+0]=t4[0]; f[i*4+1]=t4[1]; f[i*4+2]=t4[2]; f[i*4+3]=t4[3];
      }
      #pragma unroll
      for (int cc = 0; cc < 4; ++cc) {
        short8 o8;
        #pragma unroll
        for (int jj = 0; jj < 8; ++jj) o8[jj] = (short)f2bf(f[cc*8+jj]);
        const int c16 = half * 4 + cc;
        *(short8*)(lds + row * 128 + ((c16 ^ (row & 7)) << 4)) = o8;
      }
    }
    {
      short8 z8;
      #pragma unroll
      for (int jj = 0; jj < 8; ++jj) z8[jj] = 0;
      if (half == 0) {
        const float4v* asrc = (const float4v*)(act + (size_t)(row0 + row) * 16);
        float g2[16];
        #pragma unroll
        for (int i = 0; i < 4; ++i) {
          const float4v t4 = asrc[i];
          g2[i*4+0]=t4[0]; g2[i*4+1]=t4[1]; g2[i*4+2]=t4[2]; g2[i*4+3]=t4[3];
        }
        #pragma unroll
        for (int cc = 0; cc < 2; ++cc) {
          short8 o8;
          #pragma unroll
          for (int jj = 0; jj < 8; ++jj) o8[jj] = (short)f2bf(g2[cc*8+jj]);
          *(short8*)(lds + 65536 + row * 128 + ((cc ^ (row & 7)) << 4)) = o8;
        }
        #pragma unroll
        for (int cc = 2; cc < 4; ++cc)
          *(short8*)(lds + 65536 + row * 128 + ((cc ^ (row & 7)) << 4)) = z8;
      } else {
        #pragma unroll
        for (int cc = 4; cc < 8; ++cc)
          *(short8*)(lds + 65536 + row * 128 + ((cc ^ (row & 7)) << 4)) = z8;
      }
    }
  }
  // B-tiles: W_e inline f32->bf16
  {
    const int colL = tid >> 1;
    const int col  = col0 + colL;
    const int half = tid & 1;
    {
      const float4v* src = (const float4v*)(W_e + (size_t)col * DIN + half * 32);
      float f[32];
      #pragma unroll
      for (int i = 0; i < 8; ++i) {
        const float4v t4 = src[i];
        f[i*4+0]=t4[0]; f[i*4+1]=t4[1]; f[i*4+2]=t4[2]; f[i*4+3]=t4[3];
      }
      #pragma unroll
      for (int cc = 0; cc < 4; ++cc) {
        short8 o8;
        #pragma unroll
        for (int jj = 0; jj < 8; ++jj) o8[jj] = (short)f2bf(f[cc*8+jj]);
        const int c16 = half * 4 + cc;
        *(short8*)(lds + 32768 + colL * 128 + ((c16 ^ (colL & 7)) << 4)) = o8;
      }
    }
    {
      short8 z8;
      #pragma unroll
      for (int jj = 0; jj < 8; ++jj) z8[jj] = 0;
      if (half == 0) {
        const float4v* src = (const float4v*)(W_e + (size_t)col * DIN + 64);
        float g2[16];
        #pragma unroll
        for (int i = 0; i < 4; ++i) {
          const float4v t4 = src[i];
          g2[i*4+0]=t4[0]; g2[i*4+1]=t4[1]; g2[i*4+2]=t4[2]; g2[i*4+3]=t4[3];
        }
        #pragma unroll
        for (int cc = 0; cc < 2; ++cc) {
          short8 o8;
          #pragma unroll
          for (int jj = 0; jj < 8; ++jj) o8[jj] = (short)f2bf(g2[cc*8+jj]);
          *(short8*)(lds + 98304 + colL * 128 + ((cc ^ (colL & 7)) << 4)) = o8;
        }
        #pragma unroll
        for (int cc = 2; cc < 4; ++cc)
          *(short8*)(lds + 98304 + colL * 128 + ((cc ^ (colL & 7)) << 4)) = z8;
      } else {
        #pragma unroll
        for (int cc = 4; cc < 8; ++cc)
          *(short8*)(lds + 98304 + colL * 128 + ((cc ^ (colL & 7)) << 4)) = z8;
      }
    }
  }
  __syncthreads();

  f32x4 acc[8][4];
  #pragma unroll
  for (int m = 0; m < 8; ++m)
    #pragma unroll
    for (int n = 0; n < 4; ++n) acc[m][n] = f32x4{0.f, 0.f, 0.f, 0.f};

  #pragma unroll
  for (int q = 0; q < 2; ++q) {
    const unsigned char* bufp = lds + q * 65536;
    short8 bfr[4][2];
    #pragma unroll
    for (int n = 0; n < 4; ++n) {
      const int col = wc * 64 + n * 16 + cl;
      #pragma unroll
      for (int ks = 0; ks < 2; ++ks)
        bfr[n][ks] = *(const short8*)(bufp + 32768 + col * 128 +
                                      ((((ks << 2) + kgrp) ^ (col & 7)) << 4));
    }
    #pragma unroll
    for (int g = 0; g < 4; ++g) {
      short8 af[2][2];
      #pragma unroll
      for (int mm = 0; mm < 2; ++mm) {
        const int row = wr * 128 + (g * 2 + mm) * 16 + cl;
        #pragma unroll
        for (int ks = 0; ks < 2; ++ks)
          af[mm][ks] = *(const short8*)(bufp + row * 128 +
                                        ((((ks << 2) + kgrp) ^ (row & 7)) << 4));
      }
      #pragma unroll
      for (int ks = 0; ks < 2; ++ks)
        #pragma unroll
        for (int mm = 0; mm < 2; ++mm)
          #pragma unroll
          for (int n = 0; n < 4; ++n)
            acc[g * 2 + mm][n] = __builtin_amdgcn_mfma_f32_16x16x32_bf16(
                af[mm][ks], bfr[n][ks], acc[g * 2 + mm][n], 0, 0, 0);
    }
  }

  #pragma unroll
  for (int m = 0; m < 8; ++m) {
    #pragma unroll
    for (int n = 0; n < 4; ++n) {
      const int gc = col0 + wc * 64 + n * 16 + cl;
      const float be = b_e[gc];
      #pragma unroll
      for (int e2 = 0; e2 < 4; ++e2) {
        const int gr = row0 + wr * 128 + m * 16 + rg + e2;
        u[(size_t)gr * H_ + gc] = f2bf(fmaxf(acc[m][n][e2] + be, 0.f));
      }
    }
  }
}

// ---------------------------------------------------------------------------
// Kernel 2: B-projection GEMM, re-shaped for 2 blocks/CU TLP.
// BM=128, BN=256, BK=32; 512 threads = 8 waves (2M x 4N), wave C = 64x64
// (4m x 4n frags, acc = 64 VGPR). LDS dbuf = 2 x 24KB = 48KB -> with
// __launch_bounds__(512,4) two blocks/CU (4 waves/SIMD): co-resident block
// hides the other's barrier drains. Counted-vmcnt schedule as R9 (proven):
//   stageA(q+1)[1 rnd] ; bfr reads ; lgkm0+bar ; stageB(q+2)[2 rnds,
//   interleaved in setprio'd MFMA] ; vmcnt(2) [tails: 0] ; bar
// Swizzle for 64B rows: c16 ^= (row>>1)&3 (8 rows -> 8 bank-slots, 2-way
// residual = free); pre-swizzled global source + swizzled ds_read.
// Grid 512: X=bid&7, mt = X*32 + (j>>1), nt = j&1 (same-XCD A-panel pairs).
// CE epilogue: wave wr owns exactly chunk mt*2+wr (64 rows, m=0..3).
// ---------------------------------------------------------------------------
__global__ __launch_bounds__(512, 4) void gemm_bproj(
    const unsigned short* __restrict__ A, const unsigned short* __restrict__ Bt,
    unsigned short* __restrict__ Cb,
    const float* __restrict__ powa, float* __restrict__ e)
{
  constexpr int NT = 16;               // K = 512 / 32
  constexpr int ABYTES = 128 * 32 * 2; // 8192
  constexpr int TOT = ABYTES + 256 * 32 * 2;  // 24576
  __shared__ __align__(16) unsigned char lds[2 * TOT];

  const int tid  = threadIdx.x;
  const int lane = tid & 63;
  const int wid  = tid >> 6;
  const int wr   = wid >> 2;          // 0..1 (M)
  const int wc   = wid & 3;           // 0..3 (N)
  const int cl   = lane & 15;
  const int kgrp = lane >> 4;
  const int rg   = kgrp * 4;

  const int X  = (int)blockIdx.x & 7;
  const int j  = (int)blockIdx.x >> 3;       // 0..63
  const int mt = X * 32 + (j >> 1);          // 0..255
  const int nt = j & 1;
  const int row0 = mt * 128, col0 = nt * 256;

  auto stageA = [&](int q, int buf) {        // 1 round (8KB)
    const int k0 = q * 32;
    const int o   = tid * 16;
    const int row = o >> 6;
    const int c16 = (o >> 4) & 3;
    const int kk  = (c16 ^ ((row >> 1) & 3)) << 3;
    __builtin_amdgcn_global_load_lds(
        (const __attribute__((address_space(1))) void*)
            (A + (size_t)(row0 + row) * H_ + k0 + kk),
        (__attribute__((address_space(3))) void*)(lds + buf * TOT + o),
        16, 0, 0);
  };
  auto stageB_round = [&](int q, int buf, int r) {   // r = 0,1 (8KB each)
    const int k0 = q * 32;
    const int o   = r * 8192 + tid * 16;
    const int col = o >> 6;
    const int c16 = (o >> 4) & 3;
    const int kk  = (c16 ^ ((col >> 1) & 3)) << 3;
    __builtin_amdgcn_global_load_lds(
        (const __attribute__((address_space(1))) void*)
            (Bt + (size_t)(col0 + col) * H_ + k0 + kk),
        (__attribute__((address_space(3))) void*)(lds + buf * TOT + ABYTES + o),
        16, 0, 0);
  };

  f32x4 acc[4][4];
  #pragma unroll
  for (int m = 0; m < 4; ++m)
    #pragma unroll
    for (int n = 0; n < 4; ++n) acc[m][n] = f32x4{0.f, 0.f, 0.f, 0.f};

  // Prologue: A0,B0 -> buf0; B1 -> buf1. Wait A0+B0 (oldest 3 of 5).
  stageA(0, 0);
  stageB_round(0, 0, 0); stageB_round(0, 0, 1);
  stageB_round(1, 1, 0); stageB_round(1, 1, 1);
  asm volatile("s_waitcnt vmcnt(2)" ::: "memory");
  __builtin_amdgcn_sched_barrier(0);
  __builtin_amdgcn_s_barrier();

  for (int q = 0; q < NT; ++q) {
    const int cur = q & 1;
    const unsigned char* bufp = lds + cur * TOT;

    if (q + 1 < NT) stageA(q + 1, cur ^ 1);

    // bfr preload (4 ds_read_b128) from buf[cur].B
    short8 bfr[4];
    #pragma unroll
    for (int n = 0; n < 4; ++n) {
      const int col = wc * 64 + n * 16 + cl;
      bfr[n] = *(const short8*)(bufp + ABYTES + col * 64 +
                                ((kgrp ^ ((col >> 1) & 3)) << 4));
    }
    asm volatile("s_waitcnt lgkmcnt(0)" ::: "memory");
    __builtin_amdgcn_sched_barrier(0);
    __builtin_amdgcn_s_barrier();            // bar1: all B reads of cur done

    __builtin_amdgcn_s_setprio(1);
    #pragma unroll
    for (int g = 0; g < 4; ++g) {
      if ((g == 0 || g == 2) && q + 2 < NT)
        stageB_round(q + 2, cur, g >> 1);    // overwrite cur.B (reads done)
      const int row = wr * 64 + g * 16 + cl;
      const short8 af = *(const short8*)(bufp + row * 64 +
                                         ((kgrp ^ ((row >> 1) & 3)) << 4));
      #pragma unroll
      for (int n = 0; n < 4; ++n)
        acc[g][n] = __builtin_amdgcn_mfma_f32_16x16x32_bf16(
            af, bfr[n], acc[g][n], 0, 0, 0);
    }
    __builtin_amdgcn_s_setprio(0);

    if (q + 2 < NT) {
      asm volatile("s_waitcnt vmcnt(2)" ::: "memory");  // A(q+1),B(q+1) done
    } else if (q + 1 < NT) {
      asm volatile("s_waitcnt vmcnt(0)" ::: "memory");
    }
    __builtin_amdgcn_sched_barrier(0);
    __builtin_amdgcn_s_barrier();            // bar2
  }

  // Epilogue: v write. D[r][c]: c = lane&15, r = (lane>>4)*4 + e2
  #pragma unroll
  for (int m = 0; m < 4; ++m) {
    #pragma unroll
    for (int n = 0; n < 4; ++n) {
      const int gc = col0 + wc * 64 + n * 16 + cl;
      #pragma unroll
      for (int e2 = 0; e2 < 4; ++e2) {
        const int gr = row0 + wr * 64 + m * 16 + rg + e2;
        Cb[(size_t)gr * H_ + gc] = f2bf(acc[m][n][e2]);
      }
    }
  }

  // Chunk-end e: wave wr owns chunk mt*2+wr (rows wr*64..+63).
  // i = m*16 + rg + e2; a^{63-i} = a^{15-rg-e2} * (a^16)^{3-m}.
  {
    const int chunk = mt * 2 + wr;
    #pragma unroll
    for (int n = 0; n < 4; ++n) {
      const int h = col0 + wc * 64 + n * 16 + cl;
      const float a16 = powa[15 * H_ + h];
      float ep = 0.f;
      #pragma unroll
      for (int e2 = 0; e2 < 4; ++e2) {
        const int k = 15 - rg - e2;
        const float wk = (k == 0) ? 1.f : powa[(size_t)(k - 1) * H_ + h];
        float hsum = acc[0][n][e2];
        hsum = fmaf(hsum, a16, acc[1][n][e2]);
        hsum = fmaf(hsum, a16, acc[2][n][e2]);
        hsum = fmaf(hsum, a16, acc[3][n][e2]);
        ep = fmaf(wk, hsum, ep);
      }
      ep += __shfl_xor(ep, 16);
      ep += __shfl_xor(ep, 32);
      if (kgrp == 0)
        e[(size_t)chunk * H_ + h] = ep;
    }
  }
}

// ---------------------------------------------------------------------------
// Kernel 3: fused carry + scan + out-projection (R9-proven, unchanged).
// ---------------------------------------------------------------------------
__global__ __launch_bounds__(256) void scan_out(
    const unsigned int* __restrict__ v, const float* __restrict__ e,
    const float* __restrict__ aarr, const unsigned short* __restrict__ Wo,
    const float* __restrict__ b_out, float* __restrict__ y)
{
  __shared__ __align__(16) unsigned char sbytes[64 * 1024];
  const int blk = blockIdx.x;
  const int b = blk >> 5, c = blk & 31;
  const int tid = threadIdx.x;
  const int lane = tid & 63, w = tid >> 6;
  const int row_base = blk * L_;

  {
    const int h0 = tid * 2;
    const float a0 = aarr[h0], a1 = aarr[h0 + 1];
    float aL0 = a0 * a0, aL1 = a1 * a1;
    aL0 *= aL0; aL1 *= aL1;
    aL0 *= aL0; aL1 *= aL1;
    aL0 *= aL0; aL1 *= aL1;
    aL0 *= aL0; aL1 *= aL1;
    aL0 *= aL0; aL1 *= aL1;                       // a^64
    float s0 = 0.f, s1 = 0.f;
    #pragma unroll
    for (int g = 0; g < 4; ++g) {
      float ev0[8], ev1[8];
      #pragma unroll
      for (int k = 0; k < 8; ++k) {
        const size_t o = ((size_t)(b * C_ + g * 8 + k)) * H_ + h0;
        ev0[k] = e[o]; ev1[k] = e[o + 1];
      }
      #pragma unroll
      for (int k = 0; k < 8; ++k) {
        const bool pred = (g * 8 + k) < c;
        s0 = pred ? fmaf(aL0, s0, ev0[k]) : s0;
        s1 = pred ? fmaf(aL1, s1, ev1[k]) : s1;
      }
    }
    const unsigned int* vp = v + (size_t)row_base * (H_ / 2) + tid;
    #pragma unroll 8
    for (int t = 0; t < L_; ++t) {
      const unsigned int pv = vp[(size_t)t * (H_ / 2)];
      s0 = fmaf(a0, s0, bf2f((unsigned short)(pv & 0xffff)));
      s1 = fmaf(a1, s1, bf2f((unsigned short)(pv >> 16)));
      const int byte = t * 1024 + ((tid * 4) ^ ((t & 7) << 4));
      *(unsigned int*)(sbytes + byte) =
          (unsigned int)f2bf(s0) | ((unsigned int)f2bf(s1) << 16);
    }
  }
  __syncthreads();

  f32x4 acc[4];
  #pragma unroll
  for (int n = 0; n < 4; ++n) acc[n] = f32x4{0.f, 0.f, 0.f, 0.f};
  const int r = w * 16 + (lane & 15);
  const int kof = (lane >> 4) * 8;
  #pragma unroll 4
  for (int k0 = 0; k0 < H_; k0 += 32) {
    const int byte = r * 1024 + (((k0 + kof) * 2) ^ ((r & 7) << 4));
    const short8 af = *(const short8*)(sbytes + byte);
    #pragma unroll
    for (int n = 0; n < 4; ++n) {
      const short8 bf = *(const short8*)(Wo + (size_t)(n * 16 + (lane & 15)) * H_ + k0 + kof);
      acc[n] = __builtin_amdgcn_mfma_f32_16x16x32_bf16(af, bf, acc[n], 0, 0, 0);
    }
  }
  const int cl = lane & 15, rg = (lane >> 4) * 4;
  #pragma unroll
  for (int n = 0; n < 4; ++n) {
    #pragma unroll
    for (int e2 = 0; e2 < 4; ++e2) {
      const int gr = row_base + w * 16 + rg + e2;
      const int gc = n * 16 + cl;
      y[(size_t)gr * O_ + gc] = acc[n][e2] + b_out[gc];
    }
  }
}

// ---------------------------------------------------------------------------
extern "C" void kernel_launch(void* const* d_in, const int* in_sizes, int n_in,
                              void* d_out, int out_size, void* d_ws, size_t ws_size,
                              hipStream_t stream)
{
  const float* obs   = (const float*)d_in[0];
  const float* act   = (const float*)d_in[1];
  const float* W_e   = (const float*)d_in[2];
  const float* b_e   = (const float*)d_in[3];
  const float* a_raw = (const float*)d_in[4];
  const float* W_B   = (const float*)d_in[5];
  const float* W_out = (const float*)d_in[6];
  const float* b_out = (const float*)d_in[7];
  float* y = (float*)d_out;

  char* w = (char*)d_ws;
  auto carve = [&](size_t bytes) {
    char* p = w; w += (bytes + 255) & ~(size_t)255; return p;
  };
  unsigned short* WBb   = (unsigned short*)carve((size_t)H_ * H_ * 2);
  unsigned short* Woutb = (unsigned short*)carve((size_t)O_ * H_ * 2);
  float*          aarr  = (float*)carve((size_t)H_ * 4);
  float*          powa  = (float*)carve((size_t)16 * H_ * 4);
  unsigned short* u     = (unsigned short*)carve((size_t)BT_ * H_ * 2);   // 33.5 MB
  unsigned short* v     = (unsigned short*)carve((size_t)BT_ * H_ * 2);   // 33.5 MB
  float*          e     = (float*)carve((size_t)NCHUNK * H_ * 4);         // 1 MB

  // 1) embed (+ inline weight prep) -> u
  embed_gemm<<<256, 512, 0, stream>>>(obs, act, W_e, b_e, a_raw, W_B, W_out,
                                      WBb, Woutb, aarr, powa, u);
  // 2) v = u @ WB^T (128x256 tile, 2 blocks/CU counted-vmcnt); emits e
  gemm_bproj<<<512, 512, 0, stream>>>(u, WBb, v, powa, e);
  // 3) fused carry + scan + out-projection -> y
  scan_out<<<NCHUNK, 256, 0, stream>>>((const unsigned int*)v, e, aarr,
                                       Woutb, b_out, y);
}

// Round 12
// 68.344 us; speedup vs baseline: 1.5048x; 1.0437x over previous
//
#include <hip/hip_runtime.h>
#include <hip/hip_bf16.h>

// Problem constants
#define B_    16
#define T_    2048
#define H_    512
#define BT_   32768      // B*T tokens
#define DIN   80         // obs 64 + act 16
#define L_    64
#define C_    32
#define O_    64
#define NCHUNK (BT_ / L_)  // 512 chunks

typedef __attribute__((ext_vector_type(8))) short short8;
typedef __attribute__((ext_vector_type(4))) float f32x4;
typedef __attribute__((ext_vector_type(4))) float float4v;

__device__ __forceinline__ float bf2f(unsigned short u) {
  union { unsigned int i; float f; } x; x.i = ((unsigned int)u) << 16; return x.f;
}
__device__ __forceinline__ unsigned short f2bf(float f) {
  union { float f; unsigned int i; } x; x.f = f;
  unsigned int r = x.i + 0x7fffu + ((x.i >> 16) & 1u);
  return (unsigned short)(r >> 16);
}

#define WB_N  (H_ * H_)
#define WO_N  (O_ * H_)

// ---------------------------------------------------------------------------
// Kernel 1: embed GEMM with inline prep (R9-proven, unchanged).
// u = relu(concat(obs,act) @ We^T + b_e); prologue preps WBb/Woutb/aarr/powa.
// XCD mapping: X = bid&7 writes u rows [X*16*256, (X+1)*16*256) -> that
// XCD's L2 holds its u slice for bproj (same mapping there).
// ---------------------------------------------------------------------------
__global__ __launch_bounds__(512) void embed_gemm(
    const float* __restrict__ obs, const float* __restrict__ act,
    const float* __restrict__ W_e, const float* __restrict__ b_e,
    const float* __restrict__ a_raw, const float* __restrict__ W_B,
    const float* __restrict__ W_out,
    unsigned short* __restrict__ WBb, unsigned short* __restrict__ Woutb,
    float* __restrict__ aarr, float* __restrict__ powa,
    unsigned short* __restrict__ u)
{
  __shared__ __align__(16) unsigned char lds[131072];

  const int tid  = threadIdx.x;
  const int lane = tid & 63;
  const int wid  = tid >> 6;
  const int wr   = wid >> 2;
  const int wc   = wid & 3;
  const int cl   = lane & 15;
  const int kgrp = lane >> 4;
  const int rg   = kgrp * 4;

  const int X  = (int)blockIdx.x & 7;
  const int j  = (int)blockIdx.x >> 3;
  const int mt = X * 16 + (j >> 1);
  const int nt = j & 1;
  const int row0 = mt * 256, col0 = nt * 256;

  // Prologue: strided prep
  {
    const int g = (int)blockIdx.x * 512 + tid;
    #pragma unroll
    for (int r = 0; r < 2; ++r) {
      const int idx = g * 2 + r;
      WBb[idx] = f2bf(W_B[idx]);
    }
    if (g < WO_N) Woutb[g] = f2bf(W_out[g]);
    if (g < H_) {
      const float a = tanhf(a_raw[g]);
      aarr[g] = a;
      float p = a;
      #pragma unroll
      for (int i = 0; i < 16; ++i) { powa[i * H_ + g] = p; p *= a; }
    }
  }

  // A-tiles: inline f32->bf16, swizzled ds_write
  {
    const int row  = tid >> 1;
    const int half = tid & 1;
    {
      const float4v* src = (const float4v*)(obs + (size_t)(row0 + row) * 64 + half * 32);
      float f[32];
      #pragma unroll
      for (int i = 0; i < 8; ++i) {
        const float4v t4 = src[i];
        f[i*4+0]=t4[0]; f[i*4+1]=t4[1]; f[i*4+2]=t4[2]; f[i*4+3]=t4[3];
      }
      #pragma unroll
      for (int cc = 0; cc < 4; ++cc) {
        short8 o8;
        #pragma unroll
        for (int jj = 0; jj < 8; ++jj) o8[jj] = (short)f2bf(f[cc*8+jj]);
        const int c16 = half * 4 + cc;
        *(short8*)(lds + row * 128 + ((c16 ^ (row & 7)) << 4)) = o8;
      }
    }
    {
      short8 z8;
      #pragma unroll
      for (int jj = 0; jj < 8; ++jj) z8[jj] = 0;
      if (half == 0) {
        const float4v* asrc = (const float4v*)(act + (size_t)(row0 + row) * 16);
        float g2[16];
        #pragma unroll
        for (int i = 0; i < 4; ++i) {
          const float4v t4 = asrc[i];
          g2[i*4+0]=t4[0]; g2[i*4+1]=t4[1]; g2[i*4+2]=t4[2]; g2[i*4+3]=t4[3];
        }
        #pragma unroll
        for (int cc = 0; cc < 2; ++cc) {
          short8 o8;
          #pragma unroll
          for (int jj = 0; jj < 8; ++jj) o8[jj] = (short)f2bf(g2[cc*8+jj]);
          *(short8*)(lds + 65536 + row * 128 + ((cc ^ (row & 7)) << 4)) = o8;
        }
        #pragma unroll
        for (int cc = 2; cc < 4; ++cc)
          *(short8*)(lds + 65536 + row * 128 + ((cc ^ (row & 7)) << 4)) = z8;
      } else {
        #pragma unroll
        for (int cc = 4; cc < 8; ++cc)
          *(short8*)(lds + 65536 + row * 128 + ((cc ^ (row & 7)) << 4)) = z8;
      }
    }
  }
  // B-tiles: W_e inline f32->bf16
  {
    const int colL = tid >> 1;
    const int col  = col0 + colL;
    const int half = tid & 1;
    {
      const float4v* src = (const float4v*)(W_e + (size_t)col * DIN + half * 32);
      float f[32];
      #pragma unroll
      for (int i = 0; i < 8; ++i) {
        const float4v t4 = src[i];
        f[i*4+0]=t4[0]; f[i*4+1]=t4[1]; f[i*4+2]=t4[2]; f[i*4+3]=t4[3];
      }
      #pragma unroll
      for (int cc = 0; cc < 4; ++cc) {
        short8 o8;
        #pragma unroll
        for (int jj = 0; jj < 8; ++jj) o8[jj] = (short)f2bf(f[cc*8+jj]);
        const int c16 = half * 4 + cc;
        *(short8*)(lds + 32768 + colL * 128 + ((c16 ^ (colL & 7)) << 4)) = o8;
      }
    }
    {
      short8 z8;
      #pragma unroll
      for (int jj = 0; jj < 8; ++jj) z8[jj] = 0;
      if (half == 0) {
        const float4v* src = (const float4v*)(W_e + (size_t)col * DIN + 64);
        float g2[16];
        #pragma unroll
        for (int i = 0; i < 4; ++i) {
          const float4v t4 = src[i];
          g2[i*4+0]=t4[0]; g2[i*4+1]=t4[1]; g2[i*4+2]=t4[2]; g2[i*4+3]=t4[3];
        }
        #pragma unroll
        for (int cc = 0; cc < 2; ++cc) {
          short8 o8;
          #pragma unroll
          for (int jj = 0; jj < 8; ++jj) o8[jj] = (short)f2bf(g2[cc*8+jj]);
          *(short8*)(lds + 98304 + colL * 128 + ((cc ^ (colL & 7)) << 4)) = o8;
        }
        #pragma unroll
        for (int cc = 2; cc < 4; ++cc)
          *(short8*)(lds + 98304 + colL * 128 + ((cc ^ (colL & 7)) << 4)) = z8;
      } else {
        #pragma unroll
        for (int cc = 4; cc < 8; ++cc)
          *(short8*)(lds + 98304 + colL * 128 + ((cc ^ (colL & 7)) << 4)) = z8;
      }
    }
  }
  __syncthreads();

  f32x4 acc[8][4];
  #pragma unroll
  for (int m = 0; m < 8; ++m)
    #pragma unroll
    for (int n = 0; n < 4; ++n) acc[m][n] = f32x4{0.f, 0.f, 0.f, 0.f};

  #pragma unroll
  for (int q = 0; q < 2; ++q) {
    const unsigned char* bufp = lds + q * 65536;
    short8 bfr[4][2];
    #pragma unroll
    for (int n = 0; n < 4; ++n) {
      const int col = wc * 64 + n * 16 + cl;
      #pragma unroll
      for (int ks = 0; ks < 2; ++ks)
        bfr[n][ks] = *(const short8*)(bufp + 32768 + col * 128 +
                                      ((((ks << 2) + kgrp) ^ (col & 7)) << 4));
    }
    #pragma unroll
    for (int g = 0; g < 4; ++g) {
      short8 af[2][2];
      #pragma unroll
      for (int mm = 0; mm < 2; ++mm) {
        const int row = wr * 128 + (g * 2 + mm) * 16 + cl;
        #pragma unroll
        for (int ks = 0; ks < 2; ++ks)
          af[mm][ks] = *(const short8*)(bufp + row * 128 +
                                        ((((ks << 2) + kgrp) ^ (row & 7)) << 4));
      }
      #pragma unroll
      for (int ks = 0; ks < 2; ++ks)
        #pragma unroll
        for (int mm = 0; mm < 2; ++mm)
          #pragma unroll
          for (int n = 0; n < 4; ++n)
            acc[g * 2 + mm][n] = __builtin_amdgcn_mfma_f32_16x16x32_bf16(
                af[mm][ks], bfr[n][ks], acc[g * 2 + mm][n], 0, 0, 0);
    }
  }

  #pragma unroll
  for (int m = 0; m < 8; ++m) {
    #pragma unroll
    for (int n = 0; n < 4; ++n) {
      const int gc = col0 + wc * 64 + n * 16 + cl;
      const float be = b_e[gc];
      #pragma unroll
      for (int e2 = 0; e2 < 4; ++e2) {
        const int gr = row0 + wr * 128 + m * 16 + rg + e2;
        u[(size_t)gr * H_ + gc] = f2bf(fmaxf(acc[m][n][e2] + be, 0.f));
      }
    }
  }
}

// ---------------------------------------------------------------------------
// Kernel 2: B-projection GEMM (R9-proven 256x256 counted-vmcnt, unchanged).
// XCD X produces v rows (and e chunks [64X, 64X+64)) in its own L2.
// ---------------------------------------------------------------------------
__global__ __launch_bounds__(512) void gemm_bproj(
    const unsigned short* __restrict__ A, const unsigned short* __restrict__ Bt,
    unsigned short* __restrict__ Cb,
    const float* __restrict__ powa, float* __restrict__ e)
{
  constexpr int NT = 8;
  __shared__ __align__(16) unsigned char lds[131072];

  const int tid  = threadIdx.x;
  const int lane = tid & 63;
  const int wid  = tid >> 6;
  const int wr   = wid >> 2;
  const int wc   = wid & 3;
  const int cl   = lane & 15;
  const int kgrp = lane >> 4;
  const int rg   = kgrp * 4;

  const int X  = (int)blockIdx.x & 7;
  const int j  = (int)blockIdx.x >> 3;
  const int mt = X * 16 + (j >> 1);
  const int nt = j & 1;
  const int row0 = mt * 256, col0 = nt * 256;

  auto stageA = [&](int q, int buf) {
    const int k0 = q * 64;
    #pragma unroll
    for (int r = 0; r < 4; ++r) {
      const int o   = r * 8192 + tid * 16;
      const int row = o >> 7;
      const int c16 = (o >> 4) & 7;
      const int kk  = (c16 ^ (row & 7)) << 3;
      __builtin_amdgcn_global_load_lds(
          (const __attribute__((address_space(1))) void*)
              (A + (size_t)(row0 + row) * H_ + k0 + kk),
          (__attribute__((address_space(3))) void*)(lds + buf * 65536 + o),
          16, 0, 0);
    }
  };
  auto stageB_round = [&](int q, int buf, int r) {
    const int k0 = q * 64;
    const int o   = r * 8192 + tid * 16;
    const int col = o >> 7;
    const int c16 = (o >> 4) & 7;
    const int kk  = (c16 ^ (col & 7)) << 3;
    __builtin_amdgcn_global_load_lds(
        (const __attribute__((address_space(1))) void*)
            (Bt + (size_t)(col0 + col) * H_ + k0 + kk),
        (__attribute__((address_space(3))) void*)(lds + buf * 65536 + 32768 + o),
        16, 0, 0);
  };

  f32x4 acc[8][4];
  #pragma unroll
  for (int m = 0; m < 8; ++m)
    #pragma unroll
    for (int n = 0; n < 4; ++n) acc[m][n] = f32x4{0.f, 0.f, 0.f, 0.f};

  stageA(0, 0);
  #pragma unroll
  for (int r = 0; r < 4; ++r) stageB_round(0, 0, r);
  #pragma unroll
  for (int r = 0; r < 4; ++r) stageB_round(1, 1, r);
  asm volatile("s_waitcnt vmcnt(4)" ::: "memory");
  __builtin_amdgcn_sched_barrier(0);
  __builtin_amdgcn_s_barrier();

  for (int q = 0; q < NT; ++q) {
    const int cur = q & 1;
    const unsigned char* bufp = lds + cur * 65536;

    if (q + 1 < NT) stageA(q + 1, cur ^ 1);

    short8 bfr[4][2];
    #pragma unroll
    for (int n = 0; n < 4; ++n) {
      const int col = wc * 64 + n * 16 + cl;
      #pragma unroll
      for (int ks = 0; ks < 2; ++ks)
        bfr[n][ks] = *(const short8*)(bufp + 32768 + col * 128 +
                                      ((((ks << 2) + kgrp) ^ (col & 7)) << 4));
    }
    asm volatile("s_waitcnt lgkmcnt(0)" ::: "memory");
    __builtin_amdgcn_sched_barrier(0);
    __builtin_amdgcn_s_barrier();

    __builtin_amdgcn_s_setprio(1);
    #pragma unroll
    for (int g = 0; g < 4; ++g) {
      if (q + 2 < NT) stageB_round(q + 2, cur, g);
      short8 af[2][2];
      #pragma unroll
      for (int mm = 0; mm < 2; ++mm) {
        const int row = wr * 128 + (g * 2 + mm) * 16 + cl;
        #pragma unroll
        for (int ks = 0; ks < 2; ++ks)
          af[mm][ks] = *(const short8*)(bufp + row * 128 +
                                        ((((ks << 2) + kgrp) ^ (row & 7)) << 4));
      }
      #pragma unroll
      for (int ks = 0; ks < 2; ++ks)
        #pragma unroll
        for (int mm = 0; mm < 2; ++mm)
          #pragma unroll
          for (int n = 0; n < 4; ++n)
            acc[g * 2 + mm][n] = __builtin_amdgcn_mfma_f32_16x16x32_bf16(
                af[mm][ks], bfr[n][ks], acc[g * 2 + mm][n], 0, 0, 0);
    }
    __builtin_amdgcn_s_setprio(0);

    if (q + 2 < NT) {
      asm volatile("s_waitcnt vmcnt(4)" ::: "memory");
    } else if (q + 1 < NT) {
      asm volatile("s_waitcnt vmcnt(0)" ::: "memory");
    }
    __builtin_amdgcn_sched_barrier(0);
    __builtin_amdgcn_s_barrier();
  }

  #pragma unroll
  for (int m = 0; m < 8; ++m) {
    #pragma unroll
    for (int n = 0; n < 4; ++n) {
      const int gc = col0 + wc * 64 + n * 16 + cl;
      #pragma unroll
      for (int e2 = 0; e2 < 4; ++e2) {
        const int gr = row0 + wr * 128 + m * 16 + rg + e2;
        Cb[(size_t)gr * H_ + gc] = f2bf(acc[m][n][e2]);
      }
    }
  }

  #pragma unroll
  for (int c = 0; c < 2; ++c) {
    const int chunk = ((row0 + wr * 128) >> 6) + c;
    #pragma unroll
    for (int n = 0; n < 4; ++n) {
      const int h = col0 + wc * 64 + n * 16 + cl;
      const float a16 = powa[15 * H_ + h];
      float ep = 0.f;
      #pragma unroll
      for (int e2 = 0; e2 < 4; ++e2) {
        const int k = 15 - rg - e2;
        const float wk = (k == 0) ? 1.f : powa[(size_t)(k - 1) * H_ + h];
        float hsum = acc[c * 4 + 0][n][e2];
        hsum = fmaf(hsum, a16, acc[c * 4 + 1][n][e2]);
        hsum = fmaf(hsum, a16, acc[c * 4 + 2][n][e2]);
        hsum = fmaf(hsum, a16, acc[c * 4 + 3][n][e2]);
        ep = fmaf(wk, hsum, ep);
      }
      ep += __shfl_xor(ep, 16);
      ep += __shfl_xor(ep, 32);
      if (kgrp == 0)
        e[(size_t)chunk * H_ + h] = ep;
    }
  }
}

// ---------------------------------------------------------------------------
// Kernel 3: fused carry + scan + out-projection (R9 body, ONE change:
// XCD-aligned chunk mapping). bproj's XCD X produced v rows / e entries for
// chunks [64X, 64X+64) in its L2; dispatch round-robins blocks bid -> XCD
// bid%8, so chunk = (bid&7)*64 + (bid>>3) puts the consumer on the
// producer's XCD -> v reads hit L2 instead of HBM (cross-kernel T1).
// ---------------------------------------------------------------------------
__global__ __launch_bounds__(256) void scan_out(
    const unsigned int* __restrict__ v, const float* __restrict__ e,
    const float* __restrict__ aarr, const unsigned short* __restrict__ Wo,
    const float* __restrict__ b_out, float* __restrict__ y)
{
  __shared__ __align__(16) unsigned char sbytes[64 * 1024];
  const int blk = ((int)blockIdx.x & 7) * 64 + ((int)blockIdx.x >> 3);
  const int b = blk >> 5, c = blk & 31;
  const int tid = threadIdx.x;
  const int lane = tid & 63, w = tid >> 6;
  const int row_base = blk * L_;

  {
    const int h0 = tid * 2;
    const float a0 = aarr[h0], a1 = aarr[h0 + 1];
    float aL0 = a0 * a0, aL1 = a1 * a1;
    aL0 *= aL0; aL1 *= aL1;
    aL0 *= aL0; aL1 *= aL1;
    aL0 *= aL0; aL1 *= aL1;
    aL0 *= aL0; aL1 *= aL1;
    aL0 *= aL0; aL1 *= aL1;                       // a^64
    float s0 = 0.f, s1 = 0.f;
    #pragma unroll
    for (int g = 0; g < 4; ++g) {
      float ev0[8], ev1[8];
      #pragma unroll
      for (int k = 0; k < 8; ++k) {
        const size_t o = ((size_t)(b * C_ + g * 8 + k)) * H_ + h0;
        ev0[k] = e[o]; ev1[k] = e[o + 1];
      }
      #pragma unroll
      for (int k = 0; k < 8; ++k) {
        const bool pred = (g * 8 + k) < c;
        s0 = pred ? fmaf(aL0, s0, ev0[k]) : s0;
        s1 = pred ? fmaf(aL1, s1, ev1[k]) : s1;
      }
    }
    const unsigned int* vp = v + (size_t)row_base * (H_ / 2) + tid;
    #pragma unroll 8
    for (int t = 0; t < L_; ++t) {
      const unsigned int pv = vp[(size_t)t * (H_ / 2)];
      s0 = fmaf(a0, s0, bf2f((unsigned short)(pv & 0xffff)));
      s1 = fmaf(a1, s1, bf2f((unsigned short)(pv >> 16)));
      const int byte = t * 1024 + ((tid * 4) ^ ((t & 7) << 4));
      *(unsigned int*)(sbytes + byte) =
          (unsigned int)f2bf(s0) | ((unsigned int)f2bf(s1) << 16);
    }
  }
  __syncthreads();

  f32x4 acc[4];
  #pragma unroll
  for (int n = 0; n < 4; ++n) acc[n] = f32x4{0.f, 0.f, 0.f, 0.f};
  const int r = w * 16 + (lane & 15);
  const int kof = (lane >> 4) * 8;
  #pragma unroll 4
  for (int k0 = 0; k0 < H_; k0 += 32) {
    const int byte = r * 1024 + (((k0 + kof) * 2) ^ ((r & 7) << 4));
    const short8 af = *(const short8*)(sbytes + byte);
    #pragma unroll
    for (int n = 0; n < 4; ++n) {
      const short8 bf = *(const short8*)(Wo + (size_t)(n * 16 + (lane & 15)) * H_ + k0 + kof);
      acc[n] = __builtin_amdgcn_mfma_f32_16x16x32_bf16(af, bf, acc[n], 0, 0, 0);
    }
  }
  const int cl = lane & 15, rg = (lane >> 4) * 4;
  #pragma unroll
  for (int n = 0; n < 4; ++n) {
    #pragma unroll
    for (int e2 = 0; e2 < 4; ++e2) {
      const int gr = row_base + w * 16 + rg + e2;
      const int gc = n * 16 + cl;
      y[(size_t)gr * O_ + gc] = acc[n][e2] + b_out[gc];
    }
  }
}

// ---------------------------------------------------------------------------
extern "C" void kernel_launch(void* const* d_in, const int* in_sizes, int n_in,
                              void* d_out, int out_size, void* d_ws, size_t ws_size,
                              hipStream_t stream)
{
  const float* obs   = (const float*)d_in[0];
  const float* act   = (const float*)d_in[1];
  const float* W_e   = (const float*)d_in[2];
  const float* b_e   = (const float*)d_in[3];
  const float* a_raw = (const float*)d_in[4];
  const float* W_B   = (const float*)d_in[5];
  const float* W_out = (const float*)d_in[6];
  const float* b_out = (const float*)d_in[7];
  float* y = (float*)d_out;

  char* w = (char*)d_ws;
  auto carve = [&](size_t bytes) {
    char* p = w; w += (bytes + 255) & ~(size_t)255; return p;
  };
  unsigned short* WBb   = (unsigned short*)carve((size_t)H_ * H_ * 2);
  unsigned short* Woutb = (unsigned short*)carve((size_t)O_ * H_ * 2);
  float*          aarr  = (float*)carve((size_t)H_ * 4);
  float*          powa  = (float*)carve((size_t)16 * H_ * 4);
  unsigned short* u     = (unsigned short*)carve((size_t)BT_ * H_ * 2);   // 33.5 MB
  unsigned short* v     = (unsigned short*)carve((size_t)BT_ * H_ * 2);   // 33.5 MB
  float*          e     = (float*)carve((size_t)NCHUNK * H_ * 4);         // 1 MB

  // 1) embed (+ inline weight prep) -> u
  embed_gemm<<<256, 512, 0, stream>>>(obs, act, W_e, b_e, a_raw, W_B, W_out,
                                      WBb, Woutb, aarr, powa, u);
  // 2) v = u @ WB^T (counted-vmcnt pipeline); epilogue emits e
  gemm_bproj<<<256, 512, 0, stream>>>(u, WBb, v, powa, e);
  // 3) fused carry + scan + out-projection -> y (XCD-aligned chunks)
  scan_out<<<NCHUNK, 256, 0, stream>>>((const unsigned int*)v, e, aarr,
                                       Woutb, b_out, y);
}

// Round 13
// 68.299 us; speedup vs baseline: 1.5058x; 1.0006x over previous
//
#include <hip/hip_runtime.h>
#include <hip/hip_bf16.h>

// Problem constants
#define B_    16
#define T_    2048
#define H_    512
#define BT_   32768      // B*T tokens
#define DIN   80         // obs 64 + act 16
#define L_    64
#define C_    32
#define O_    64
#define NCHUNK (BT_ / L_)  // 512 chunks

typedef __attribute__((ext_vector_type(8))) short short8;
typedef __attribute__((ext_vector_type(4))) float f32x4;
typedef __attribute__((ext_vector_type(4))) float float4v;

__device__ __forceinline__ float bf2f(unsigned short u) {
  union { unsigned int i; float f; } x; x.i = ((unsigned int)u) << 16; return x.f;
}
__device__ __forceinline__ unsigned short f2bf(float f) {
  union { float f; unsigned int i; } x; x.f = f;
  unsigned int r = x.i + 0x7fffu + ((x.i >> 16) & 1u);
  return (unsigned short)(r >> 16);
}

#define WB_N  (H_ * H_)
#define WO_N  (O_ * H_)

// ---------------------------------------------------------------------------
// Kernel 1: embed GEMM with inline prep (R9-proven, unchanged).
// ---------------------------------------------------------------------------
__global__ __launch_bounds__(512) void embed_gemm(
    const float* __restrict__ obs, const float* __restrict__ act,
    const float* __restrict__ W_e, const float* __restrict__ b_e,
    const float* __restrict__ a_raw, const float* __restrict__ W_B,
    const float* __restrict__ W_out,
    unsigned short* __restrict__ WBb, unsigned short* __restrict__ Woutb,
    float* __restrict__ aarr, float* __restrict__ powa,
    unsigned short* __restrict__ u)
{
  __shared__ __align__(16) unsigned char lds[131072];

  const int tid  = threadIdx.x;
  const int lane = tid & 63;
  const int wid  = tid >> 6;
  const int wr   = wid >> 2;
  const int wc   = wid & 3;
  const int cl   = lane & 15;
  const int kgrp = lane >> 4;
  const int rg   = kgrp * 4;

  const int X  = (int)blockIdx.x & 7;
  const int j  = (int)blockIdx.x >> 3;
  const int mt = X * 16 + (j >> 1);
  const int nt = j & 1;
  const int row0 = mt * 256, col0 = nt * 256;

  // Prologue: strided prep
  {
    const int g = (int)blockIdx.x * 512 + tid;
    #pragma unroll
    for (int r = 0; r < 2; ++r) {
      const int idx = g * 2 + r;
      WBb[idx] = f2bf(W_B[idx]);
    }
    if (g < WO_N) Woutb[g] = f2bf(W_out[g]);
    if (g < H_) {
      const float a = tanhf(a_raw[g]);
      aarr[g] = a;
      float p = a;
      #pragma unroll
      for (int i = 0; i < 16; ++i) { powa[i * H_ + g] = p; p *= a; }
    }
  }

  // A-tiles: inline f32->bf16, swizzled ds_write
  {
    const int row  = tid >> 1;
    const int half = tid & 1;
    {
      const float4v* src = (const float4v*)(obs + (size_t)(row0 + row) * 64 + half * 32);
      float f[32];
      #pragma unroll
      for (int i = 0; i < 8; ++i) {
        const float4v t4 = src[i];
        f[i*4+0]=t4[0]; f[i*4+1]=t4[1]; f[i*4+2]=t4[2]; f[i*4+3]=t4[3];
      }
      #pragma unroll
      for (int cc = 0; cc < 4; ++cc) {
        short8 o8;
        #pragma unroll
        for (int jj = 0; jj < 8; ++jj) o8[jj] = (short)f2bf(f[cc*8+jj]);
        const int c16 = half * 4 + cc;
        *(short8*)(lds + row * 128 + ((c16 ^ (row & 7)) << 4)) = o8;
      }
    }
    {
      short8 z8;
      #pragma unroll
      for (int jj = 0; jj < 8; ++jj) z8[jj] = 0;
      if (half == 0) {
        const float4v* asrc = (const float4v*)(act + (size_t)(row0 + row) * 16);
        float g2[16];
        #pragma unroll
        for (int i = 0; i < 4; ++i) {
          const float4v t4 = asrc[i];
          g2[i*4+0]=t4[0]; g2[i*4+1]=t4[1]; g2[i*4+2]=t4[2]; g2[i*4+3]=t4[3];
        }
        #pragma unroll
        for (int cc = 0; cc < 2; ++cc) {
          short8 o8;
          #pragma unroll
          for (int jj = 0; jj < 8; ++jj) o8[jj] = (short)f2bf(g2[cc*8+jj]);
          *(short8*)(lds + 65536 + row * 128 + ((cc ^ (row & 7)) << 4)) = o8;
        }
        #pragma unroll
        for (int cc = 2; cc < 4; ++cc)
          *(short8*)(lds + 65536 + row * 128 + ((cc ^ (row & 7)) << 4)) = z8;
      } else {
        #pragma unroll
        for (int cc = 4; cc < 8; ++cc)
          *(short8*)(lds + 65536 + row * 128 + ((cc ^ (row & 7)) << 4)) = z8;
      }
    }
  }
  // B-tiles: W_e inline f32->bf16
  {
    const int colL = tid >> 1;
    const int col  = col0 + colL;
    const int half = tid & 1;
    {
      const float4v* src = (const float4v*)(W_e + (size_t)col * DIN + half * 32);
      float f[32];
      #pragma unroll
      for (int i = 0; i < 8; ++i) {
        const float4v t4 = src[i];
        f[i*4+0]=t4[0]; f[i*4+1]=t4[1]; f[i*4+2]=t4[2]; f[i*4+3]=t4[3];
      }
      #pragma unroll
      for (int cc = 0; cc < 4; ++cc) {
        short8 o8;
        #pragma unroll
        for (int jj = 0; jj < 8; ++jj) o8[jj] = (short)f2bf(f[cc*8+jj]);
        const int c16 = half * 4 + cc;
        *(short8*)(lds + 32768 + colL * 128 + ((c16 ^ (colL & 7)) << 4)) = o8;
      }
    }
    {
      short8 z8;
      #pragma unroll
      for (int jj = 0; jj < 8; ++jj) z8[jj] = 0;
      if (half == 0) {
        const float4v* src = (const float4v*)(W_e + (size_t)col * DIN + 64);
        float g2[16];
        #pragma unroll
        for (int i = 0; i < 4; ++i) {
          const float4v t4 = src[i];
          g2[i*4+0]=t4[0]; g2[i*4+1]=t4[1]; g2[i*4+2]=t4[2]; g2[i*4+3]=t4[3];
        }
        #pragma unroll
        for (int cc = 0; cc < 2; ++cc) {
          short8 o8;
          #pragma unroll
          for (int jj = 0; jj < 8; ++jj) o8[jj] = (short)f2bf(g2[cc*8+jj]);
          *(short8*)(lds + 98304 + colL * 128 + ((cc ^ (colL & 7)) << 4)) = o8;
        }
        #pragma unroll
        for (int cc = 2; cc < 4; ++cc)
          *(short8*)(lds + 98304 + colL * 128 + ((cc ^ (colL & 7)) << 4)) = z8;
      } else {
        #pragma unroll
        for (int cc = 4; cc < 8; ++cc)
          *(short8*)(lds + 98304 + colL * 128 + ((cc ^ (colL & 7)) << 4)) = z8;
      }
    }
  }
  __syncthreads();

  f32x4 acc[8][4];
  #pragma unroll
  for (int m = 0; m < 8; ++m)
    #pragma unroll
    for (int n = 0; n < 4; ++n) acc[m][n] = f32x4{0.f, 0.f, 0.f, 0.f};

  #pragma unroll
  for (int q = 0; q < 2; ++q) {
    const unsigned char* bufp = lds + q * 65536;
    short8 bfr[4][2];
    #pragma unroll
    for (int n = 0; n < 4; ++n) {
      const int col = wc * 64 + n * 16 + cl;
      #pragma unroll
      for (int ks = 0; ks < 2; ++ks)
        bfr[n][ks] = *(const short8*)(bufp + 32768 + col * 128 +
                                      ((((ks << 2) + kgrp) ^ (col & 7)) << 4));
    }
    #pragma unroll
    for (int g = 0; g < 4; ++g) {
      short8 af[2][2];
      #pragma unroll
      for (int mm = 0; mm < 2; ++mm) {
        const int row = wr * 128 + (g * 2 + mm) * 16 + cl;
        #pragma unroll
        for (int ks = 0; ks < 2; ++ks)
          af[mm][ks] = *(const short8*)(bufp + row * 128 +
                                        ((((ks << 2) + kgrp) ^ (row & 7)) << 4));
      }
      #pragma unroll
      for (int ks = 0; ks < 2; ++ks)
        #pragma unroll
        for (int mm = 0; mm < 2; ++mm)
          #pragma unroll
          for (int n = 0; n < 4; ++n)
            acc[g * 2 + mm][n] = __builtin_amdgcn_mfma_f32_16x16x32_bf16(
                af[mm][ks], bfr[n][ks], acc[g * 2 + mm][n], 0, 0, 0);
    }
  }

  #pragma unroll
  for (int m = 0; m < 8; ++m) {
    #pragma unroll
    for (int n = 0; n < 4; ++n) {
      const int gc = col0 + wc * 64 + n * 16 + cl;
      const float be = b_e[gc];
      #pragma unroll
      for (int e2 = 0; e2 < 4; ++e2) {
        const int gr = row0 + wr * 128 + m * 16 + rg + e2;
        u[(size_t)gr * H_ + gc] = f2bf(fmaxf(acc[m][n][e2] + be, 0.f));
      }
    }
  }
}

// ---------------------------------------------------------------------------
// Kernel 2: B-projection GEMM — 8-phase interleave (m201-style) on the
// proven 256x256 counted-vmcnt skeleton. Per K-tile q (cur=q&1), 4 phases,
// phase g computes m-pair {2g, 2g+1} (16 MFMA):
//   phase body: [g==0: 8 bfr reads] [4 af reads] [staging issues:
//     g0: stageA(q+1)x4; g1: stageB(q+2) r0,r1; g2: r2; g3: r3]
//   -> s_barrier -> lgkmcnt(0)+sched_barrier -> setprio(1) 16 MFMA
//   setprio(0) -> [g==3: vmcnt(4) (tails: 0)] -> s_barrier
// Safety: stageB(q+2) writes buf[cur].B only in phases 1-3, i.e. after
// phase 0's end barrier, by which every wave completed its bfr reads
// (phase-0 lgkm0 precedes phase-0 MFMA precedes the barrier). stageA(q+1)
// writes buf[cur^1].A, whose last reads finished in tile q-1. vmcnt(4) at
// g==3: in-flight order [A(q+1)x4, B(q+2)x4] -> 4 newest are B(q+2);
// A(q+1) and B(q+1) (older) drained before tile q+1's phase 0 reads them.
// ---------------------------------------------------------------------------
__global__ __launch_bounds__(512) void gemm_bproj(
    const unsigned short* __restrict__ A, const unsigned short* __restrict__ Bt,
    unsigned short* __restrict__ Cb,
    const float* __restrict__ powa, float* __restrict__ e)
{
  constexpr int NT = 8;
  __shared__ __align__(16) unsigned char lds[131072];

  const int tid  = threadIdx.x;
  const int lane = tid & 63;
  const int wid  = tid >> 6;
  const int wr   = wid >> 2;
  const int wc   = wid & 3;
  const int cl   = lane & 15;
  const int kgrp = lane >> 4;
  const int rg   = kgrp * 4;

  const int X  = (int)blockIdx.x & 7;
  const int j  = (int)blockIdx.x >> 3;
  const int mt = X * 16 + (j >> 1);
  const int nt = j & 1;
  const int row0 = mt * 256, col0 = nt * 256;

  auto stageA = [&](int q, int buf) {
    const int k0 = q * 64;
    #pragma unroll
    for (int r = 0; r < 4; ++r) {
      const int o   = r * 8192 + tid * 16;
      const int row = o >> 7;
      const int c16 = (o >> 4) & 7;
      const int kk  = (c16 ^ (row & 7)) << 3;
      __builtin_amdgcn_global_load_lds(
          (const __attribute__((address_space(1))) void*)
              (A + (size_t)(row0 + row) * H_ + k0 + kk),
          (__attribute__((address_space(3))) void*)(lds + buf * 65536 + o),
          16, 0, 0);
    }
  };
  auto stageB_round = [&](int q, int buf, int r) {
    const int k0 = q * 64;
    const int o   = r * 8192 + tid * 16;
    const int col = o >> 7;
    const int c16 = (o >> 4) & 7;
    const int kk  = (c16 ^ (col & 7)) << 3;
    __builtin_amdgcn_global_load_lds(
        (const __attribute__((address_space(1))) void*)
            (Bt + (size_t)(col0 + col) * H_ + k0 + kk),
        (__attribute__((address_space(3))) void*)(lds + buf * 65536 + 32768 + o),
        16, 0, 0);
  };

  f32x4 acc[8][4];
  #pragma unroll
  for (int m = 0; m < 8; ++m)
    #pragma unroll
    for (int n = 0; n < 4; ++n) acc[m][n] = f32x4{0.f, 0.f, 0.f, 0.f};

  // Prologue: A0,B0 -> buf0; B1 -> buf1; wait A0+B0 (8 oldest of 12).
  stageA(0, 0);
  #pragma unroll
  for (int r = 0; r < 4; ++r) stageB_round(0, 0, r);
  #pragma unroll
  for (int r = 0; r < 4; ++r) stageB_round(1, 1, r);
  asm volatile("s_waitcnt vmcnt(4)" ::: "memory");
  __builtin_amdgcn_sched_barrier(0);
  __builtin_amdgcn_s_barrier();

  for (int q = 0; q < NT; ++q) {
    const int cur = q & 1;
    const unsigned char* bufp = lds + cur * 65536;
    short8 bfr[4][2];

    #pragma unroll
    for (int g = 0; g < 4; ++g) {
      // --- phase reads ---
      if (g == 0) {
        #pragma unroll
        for (int n = 0; n < 4; ++n) {
          const int col = wc * 64 + n * 16 + cl;
          #pragma unroll
          for (int ks = 0; ks < 2; ++ks)
            bfr[n][ks] = *(const short8*)(bufp + 32768 + col * 128 +
                                          ((((ks << 2) + kgrp) ^ (col & 7)) << 4));
        }
      }
      short8 af[2][2];
      #pragma unroll
      for (int mm = 0; mm < 2; ++mm) {
        const int row = wr * 128 + (g * 2 + mm) * 16 + cl;
        #pragma unroll
        for (int ks = 0; ks < 2; ++ks)
          af[mm][ks] = *(const short8*)(bufp + row * 128 +
                                        ((((ks << 2) + kgrp) ^ (row & 7)) << 4));
      }
      // --- staging issues (distributed across phases) ---
      if (g == 0) {
        if (q + 1 < NT) stageA(q + 1, cur ^ 1);
      } else if (g == 1) {
        if (q + 2 < NT) { stageB_round(q + 2, cur, 0); stageB_round(q + 2, cur, 1); }
      } else if (g == 2) {
        if (q + 2 < NT) stageB_round(q + 2, cur, 2);
      } else {
        if (q + 2 < NT) stageB_round(q + 2, cur, 3);
      }
      // --- barrier, wait own ds-reads, MFMA ---
      __builtin_amdgcn_s_barrier();
      asm volatile("s_waitcnt lgkmcnt(0)" ::: "memory");
      __builtin_amdgcn_sched_barrier(0);
      __builtin_amdgcn_s_setprio(1);
      #pragma unroll
      for (int ks = 0; ks < 2; ++ks)
        #pragma unroll
        for (int mm = 0; mm < 2; ++mm)
          #pragma unroll
          for (int n = 0; n < 4; ++n)
            acc[g * 2 + mm][n] = __builtin_amdgcn_mfma_f32_16x16x32_bf16(
                af[mm][ks], bfr[n][ks], acc[g * 2 + mm][n], 0, 0, 0);
      __builtin_amdgcn_s_setprio(0);
      // --- end barrier (+ counted vmcnt once per K-tile) ---
      if (g == 3) {
        if (q + 2 < NT) {
          asm volatile("s_waitcnt vmcnt(4)" ::: "memory");
        } else if (q + 1 < NT) {
          asm volatile("s_waitcnt vmcnt(0)" ::: "memory");
        }
      }
      __builtin_amdgcn_sched_barrier(0);
      __builtin_amdgcn_s_barrier();
    }
  }

  // Epilogue: v write. D[r][c]: c = lane&15, r = (lane>>4)*4 + e2
  #pragma unroll
  for (int m = 0; m < 8; ++m) {
    #pragma unroll
    for (int n = 0; n < 4; ++n) {
      const int gc = col0 + wc * 64 + n * 16 + cl;
      #pragma unroll
      for (int e2 = 0; e2 < 4; ++e2) {
        const int gr = row0 + wr * 128 + m * 16 + rg + e2;
        Cb[(size_t)gr * H_ + gc] = f2bf(acc[m][n][e2]);
      }
    }
  }

  // Chunk-end e: wave spans 2 chunks (m 0..3, m 4..7).
  #pragma unroll
  for (int c = 0; c < 2; ++c) {
    const int chunk = ((row0 + wr * 128) >> 6) + c;
    #pragma unroll
    for (int n = 0; n < 4; ++n) {
      const int h = col0 + wc * 64 + n * 16 + cl;
      const float a16 = powa[15 * H_ + h];
      float ep = 0.f;
      #pragma unroll
      for (int e2 = 0; e2 < 4; ++e2) {
        const int k = 15 - rg - e2;
        const float wk = (k == 0) ? 1.f : powa[(size_t)(k - 1) * H_ + h];
        float hsum = acc[c * 4 + 0][n][e2];
        hsum = fmaf(hsum, a16, acc[c * 4 + 1][n][e2]);
        hsum = fmaf(hsum, a16, acc[c * 4 + 2][n][e2]);
        hsum = fmaf(hsum, a16, acc[c * 4 + 3][n][e2]);
        ep = fmaf(wk, hsum, ep);
      }
      ep += __shfl_xor(ep, 16);
      ep += __shfl_xor(ep, 32);
      if (kgrp == 0)
        e[(size_t)chunk * H_ + h] = ep;
    }
  }
}

// ---------------------------------------------------------------------------
// Kernel 3: fused carry + scan + out-projection (R12-proven, unchanged).
// ---------------------------------------------------------------------------
__global__ __launch_bounds__(256) void scan_out(
    const unsigned int* __restrict__ v, const float* __restrict__ e,
    const float* __restrict__ aarr, const unsigned short* __restrict__ Wo,
    const float* __restrict__ b_out, float* __restrict__ y)
{
  __shared__ __align__(16) unsigned char sbytes[64 * 1024];
  const int blk = ((int)blockIdx.x & 7) * 64 + ((int)blockIdx.x >> 3);
  const int b = blk >> 5, c = blk & 31;
  const int tid = threadIdx.x;
  const int lane = tid & 63, w = tid >> 6;
  const int row_base = blk * L_;

  {
    const int h0 = tid * 2;
    const float a0 = aarr[h0], a1 = aarr[h0 + 1];
    float aL0 = a0 * a0, aL1 = a1 * a1;
    aL0 *= aL0; aL1 *= aL1;
    aL0 *= aL0; aL1 *= aL1;
    aL0 *= aL0; aL1 *= aL1;
    aL0 *= aL0; aL1 *= aL1;
    aL0 *= aL0; aL1 *= aL1;                       // a^64
    float s0 = 0.f, s1 = 0.f;
    #pragma unroll
    for (int g = 0; g < 4; ++g) {
      float ev0[8], ev1[8];
      #pragma unroll
      for (int k = 0; k < 8; ++k) {
        const size_t o = ((size_t)(b * C_ + g * 8 + k)) * H_ + h0;
        ev0[k] = e[o]; ev1[k] = e[o + 1];
      }
      #pragma unroll
      for (int k = 0; k < 8; ++k) {
        const bool pred = (g * 8 + k) < c;
        s0 = pred ? fmaf(aL0, s0, ev0[k]) : s0;
        s1 = pred ? fmaf(aL1, s1, ev1[k]) : s1;
      }
    }
    const unsigned int* vp = v + (size_t)row_base * (H_ / 2) + tid;
    #pragma unroll 8
    for (int t = 0; t < L_; ++t) {
      const unsigned int pv = vp[(size_t)t * (H_ / 2)];
      s0 = fmaf(a0, s0, bf2f((unsigned short)(pv & 0xffff)));
      s1 = fmaf(a1, s1, bf2f((unsigned short)(pv >> 16)));
      const int byte = t * 1024 + ((tid * 4) ^ ((t & 7) << 4));
      *(unsigned int*)(sbytes + byte) =
          (unsigned int)f2bf(s0) | ((unsigned int)f2bf(s1) << 16);
    }
  }
  __syncthreads();

  f32x4 acc[4];
  #pragma unroll
  for (int n = 0; n < 4; ++n) acc[n] = f32x4{0.f, 0.f, 0.f, 0.f};
  const int r = w * 16 + (lane & 15);
  const int kof = (lane >> 4) * 8;
  #pragma unroll 4
  for (int k0 = 0; k0 < H_; k0 += 32) {
    const int byte = r * 1024 + (((k0 + kof) * 2) ^ ((r & 7) << 4));
    const short8 af = *(const short8*)(sbytes + byte);
    #pragma unroll
    for (int n = 0; n < 4; ++n) {
      const short8 bf = *(const short8*)(Wo + (size_t)(n * 16 + (lane & 15)) * H_ + k0 + kof);
      acc[n] = __builtin_amdgcn_mfma_f32_16x16x32_bf16(af, bf, acc[n], 0, 0, 0);
    }
  }
  const int cl = lane & 15, rg = (lane >> 4) * 4;
  #pragma unroll
  for (int n = 0; n < 4; ++n) {
    #pragma unroll
    for (int e2 = 0; e2 < 4; ++e2) {
      const int gr = row_base + w * 16 + rg + e2;
      const int gc = n * 16 + cl;
      y[(size_t)gr * O_ + gc] = acc[n][e2] + b_out[gc];
    }
  }
}

// ---------------------------------------------------------------------------
extern "C" void kernel_launch(void* const* d_in, const int* in_sizes, int n_in,
                              void* d_out, int out_size, void* d_ws, size_t ws_size,
                              hipStream_t stream)
{
  const float* obs   = (const float*)d_in[0];
  const float* act   = (const float*)d_in[1];
  const float* W_e   = (const float*)d_in[2];
  const float* b_e   = (const float*)d_in[3];
  const float* a_raw = (const float*)d_in[4];
  const float* W_B   = (const float*)d_in[5];
  const float* W_out = (const float*)d_in[6];
  const float* b_out = (const float*)d_in[7];
  float* y = (float*)d_out;

  char* w = (char*)d_ws;
  auto carve = [&](size_t bytes) {
    char* p = w; w += (bytes + 255) & ~(size_t)255; return p;
  };
  unsigned short* WBb   = (unsigned short*)carve((size_t)H_ * H_ * 2);
  unsigned short* Woutb = (unsigned short*)carve((size_t)O_ * H_ * 2);
  float*          aarr  = (float*)carve((size_t)H_ * 4);
  float*          powa  = (float*)carve((size_t)16 * H_ * 4);
  unsigned short* u     = (unsigned short*)carve((size_t)BT_ * H_ * 2);   // 33.5 MB
  unsigned short* v     = (unsigned short*)carve((size_t)BT_ * H_ * 2);   // 33.5 MB
  float*          e     = (float*)carve((size_t)NCHUNK * H_ * 4);         // 1 MB

  // 1) embed (+ inline weight prep) -> u
  embed_gemm<<<256, 512, 0, stream>>>(obs, act, W_e, b_e, a_raw, W_B, W_out,
                                      WBb, Woutb, aarr, powa, u);
  // 2) v = u @ WB^T (8-phase interleaved counted-vmcnt); epilogue emits e
  gemm_bproj<<<256, 512, 0, stream>>>(u, WBb, v, powa, e);
  // 3) fused carry + scan + out-projection -> y
  scan_out<<<NCHUNK, 256, 0, stream>>>((const unsigned int*)v, e, aarr,
                                       Woutb, b_out, y);
}